// Round 8
// baseline (825.967 us; speedup 1.0000x reference)
//
#include <hip/hip_runtime.h>
#include <hip/hip_bf16.h>
#include <math.h>

#define D_MODEL 2048
#define KV_DIM  1024
#define N_HEAD  16
#define N_QUERY 2
#define D_HEAD  64
#define BATCH   2
#define SEQ     2048
#define MROWS   (BATCH * SEQ)   // 4096 flattened (b, s) rows

typedef __attribute__((ext_vector_type(8))) short short8x;   // 8 bf16 = 4 VGPR
typedef __attribute__((ext_vector_type(4))) float f32x4;

// self-contained bf16 round-to-nearest-even (no header-API dependency)
__device__ __forceinline__ short f2bf_rn(float f) {
    unsigned u = __float_as_uint(f);
    unsigned r = (u + 0x7fffu + ((u >> 16) & 1u)) >> 16;
    return (short)r;
}
__device__ __forceinline__ float bf2f(short s) {
    return __uint_as_float(((unsigned)(unsigned short)s) << 16);
}

// async global->LDS, 16 B per lane. LDS dest is wave-uniform base + lane*16
// (m104/m108), so pass a wave-uniform LDS pointer; global src is per-lane.
__device__ __forceinline__ void gload_lds16(const short* g, short* l) {
    __builtin_amdgcn_global_load_lds(
        (const __attribute__((address_space(1))) void*)g,
        (__attribute__((address_space(3))) void*)l,
        16, 0, 0);
}

// ---------------------------------------------------------------------------
// fp32 -> (hi, lo) bf16 split, elementwise. n must be a multiple of 4.
// ---------------------------------------------------------------------------
__global__ __launch_bounds__(256)
void split_kernel(const float* __restrict__ in, short* __restrict__ h,
                  short* __restrict__ l, int n) {
    const int i = (blockIdx.x * 256 + threadIdx.x) * 4;
    if (i >= n) return;
    float4 v = *(const float4*)&in[i];
    short4 hv, lv;
    hv.x = f2bf_rn(v.x); lv.x = f2bf_rn(v.x - bf2f(hv.x));
    hv.y = f2bf_rn(v.y); lv.y = f2bf_rn(v.y - bf2f(hv.y));
    hv.z = f2bf_rn(v.z); lv.z = f2bf_rn(v.z - bf2f(hv.z));
    hv.w = f2bf_rn(v.w); lv.w = f2bf_rn(v.w - bf2f(hv.w));
    *(short4*)&h[i] = hv;
    *(short4*)&l[i] = lv;
}

// ---------------------------------------------------------------------------
// transpose + split: in fp32 [K][N] -> h/l bf16 [N][K]. 32x32 LDS tile
// (33-padded), coalesced on read (N-fast) and write (K-fast).
// ---------------------------------------------------------------------------
__global__ __launch_bounds__(256)
void split_tr_kernel(const float* __restrict__ in, short* __restrict__ h,
                     short* __restrict__ l, int K, int N) {
    __shared__ float t[32][33];
    const int k0 = blockIdx.y * 32;
    const int n0 = blockIdx.x * 32;
    const int c  = threadIdx.x & 31;
    const int r0 = threadIdx.x >> 5;    // 0..7
#pragma unroll
    for (int i = 0; i < 4; ++i) {
        const int r = r0 + i * 8;
        t[r][c] = in[(size_t)(k0 + r) * N + n0 + c];
    }
    __syncthreads();
#pragma unroll
    for (int i = 0; i < 4; ++i) {
        const int r = r0 + i * 8;           // output n-offset
        const float f = t[c][r];            // = in[k0+c][n0+r]
        const short hb = f2bf_rn(f);
        const size_t off = (size_t)(n0 + r) * K + k0 + c;
        h[off] = hb;
        l[off] = f2bf_rn(f - bf2f(hb));
    }
}

// ---------------------------------------------------------------------------
// bf16x3-split MFMA GEMM on pre-split inputs: C = A @ B, ~5e-5 rel err.
// A as (Ah,Al) [M][K] bf16, B pre-TRANSPOSED as (Bth,Btl) [N][K] bf16.
// 128x128 tile, BK=64, 256 thr (4 waves, 2x2 of 64x64), mfma_f32_16x16x32_bf16.
// Staging uses global_load_lds width=16: LDS dest is LINEAR (chunk c at byte
// c*16); the chunk-XOR swizzle is applied to the GLOBAL source address
// (both-sides-or-neither, guide rule #21). Position (r,v) holds global chunk
// (r, v^(r&7)), so the fragment read at (r, u^(r&7)) retrieves logical chunk
// (r,u), and the hot LDS reads stay bank-conflict-free.
// MODE: 0 = fp32 C; 1 = split (Ch,Cl) [M][N]; 2 = split TRANSPOSED [N][M]
// (for V: attention consumes Vt[d][s] rows directly).
// ---------------------------------------------------------------------------
template <int MODE>
__global__ __launch_bounds__(256)
void mgemm_bf_kernel(const short* __restrict__ Ah_g, const short* __restrict__ Al_g,
                     const short* __restrict__ Bth_g, const short* __restrict__ Btl_g,
                     float* __restrict__ C, short* __restrict__ Ch, short* __restrict__ Cl,
                     int M, int N, int K) {
    __shared__ __align__(16) short Ah[128 * 64];
    __shared__ __align__(16) short Al[128 * 64];
    __shared__ __align__(16) short Bh[128 * 64];
    __shared__ __align__(16) short Bl[128 * 64];

    const int tid  = threadIdx.x;
    const int lane = tid & 63;
    const int wid  = tid >> 6;
    const int wm   = (wid >> 1) * 64;   // wave row offset in tile
    const int wn   = (wid & 1) * 64;    // wave col offset in tile
    const int row0 = blockIdx.y * 128;
    const int col0 = blockIdx.x * 128;
    const int arow = lane & 15;
    const int kg   = lane >> 4;         // 0..3 -> k-chunk within MFMA step

    f32x4 acc[4][4];
#pragma unroll
    for (int m = 0; m < 4; ++m)
#pragma unroll
        for (int n = 0; n < 4; ++n) acc[m][n] = (f32x4)0.f;

    for (int kt = 0; kt < K; kt += 64) {
        // ---- stage A + Bt via global_load_lds: linear LDS dest, pre-swizzled
        //      global source (kcs = kc ^ (r&7) permutes 16B sub-chunks within
        //      the same 128B row segment -> coalescing preserved)
#pragma unroll
        for (int i = 0; i < 4; ++i) {
            const int c   = i * 256 + tid;      // 0..1023 chunk id
            const int r   = c >> 3;             // 0..127
            const int kc  = c & 7;              // 8-elem chunk 0..7
            const int kcs = kc ^ (r & 7);       // source-side swizzle
            const int db  = (i * 256 + (tid & 192)) * 8;  // wave-uniform dest (shorts)
            const size_t sa = (size_t)(row0 + r) * K + kt + kcs * 8;
            const size_t sb = (size_t)(col0 + r) * K + kt + kcs * 8;
            gload_lds16(&Ah_g[sa],  &Ah[db]);
            gload_lds16(&Al_g[sa],  &Al[db]);
            gload_lds16(&Bth_g[sb], &Bh[db]);
            gload_lds16(&Btl_g[sb], &Bl[db]);
        }
        __syncthreads();   // drains vmcnt(0) -> LDS-DMA complete

        // ---- 2 MFMA K-steps of 32; 3 MFMAs per (m,n) for the bf16x3 split
#pragma unroll
        for (int kk = 0; kk < 2; ++kk) {
            const int kcb = kk * 4 + kg;
            short8x ah[4], al[4];
#pragma unroll
            for (int m = 0; m < 4; ++m) {
                const int r   = wm + m * 16 + arow;
                const int idx = r * 64 + ((kcb ^ (r & 7)) << 3);
                ah[m] = *(const short8x*)&Ah[idx];
                al[m] = *(const short8x*)&Al[idx];
            }
#pragma unroll
            for (int n = 0; n < 4; ++n) {
                const int rb   = wn + n * 16 + arow;
                const int idxb = rb * 64 + ((kcb ^ (rb & 7)) << 3);
                short8x bh = *(const short8x*)&Bh[idxb];
                short8x bl = *(const short8x*)&Bl[idxb];
#pragma unroll
                for (int m = 0; m < 4; ++m) {
                    acc[m][n] = __builtin_amdgcn_mfma_f32_16x16x32_bf16(ah[m], bl, acc[m][n], 0, 0, 0);
                    acc[m][n] = __builtin_amdgcn_mfma_f32_16x16x32_bf16(al[m], bh, acc[m][n], 0, 0, 0);
                    acc[m][n] = __builtin_amdgcn_mfma_f32_16x16x32_bf16(ah[m], bh, acc[m][n], 0, 0, 0);
                }
            }
        }
        __syncthreads();
    }

    // ---- epilogue: C/D mapping col=lane&15, row=(lane>>4)*4+j [m89 verified]
#pragma unroll
    for (int m = 0; m < 4; ++m)
#pragma unroll
        for (int n = 0; n < 4; ++n) {
            const int row = row0 + wm + m * 16 + (lane >> 4) * 4;
            const int col = col0 + wn + n * 16 + (lane & 15);
            if (MODE == 2) {
                // transposed split store: Ct[col][row], 4 j-values contiguous
                const float v0 = acc[m][n][0], v1 = acc[m][n][1];
                const float v2 = acc[m][n][2], v3 = acc[m][n][3];
                const short h0 = f2bf_rn(v0), h1 = f2bf_rn(v1);
                const short h2 = f2bf_rn(v2), h3 = f2bf_rn(v3);
                const size_t off = (size_t)col * M + row;
                *(short4*)&Ch[off] = make_short4(h0, h1, h2, h3);
                *(short4*)&Cl[off] = make_short4(
                    f2bf_rn(v0 - bf2f(h0)), f2bf_rn(v1 - bf2f(h1)),
                    f2bf_rn(v2 - bf2f(h2)), f2bf_rn(v3 - bf2f(h3)));
            } else {
#pragma unroll
                for (int j = 0; j < 4; ++j) {
                    const size_t off = (size_t)(row + j) * N + col;
                    if (MODE == 1) {
                        const float val = acc[m][n][j];
                        const short hb = f2bf_rn(val);
                        Ch[off] = hb;
                        Cl[off] = f2bf_rn(val - bf2f(hb));
                    } else {
                        C[off] = acc[m][n][j];
                    }
                }
            }
        }
}

// ---------------------------------------------------------------------------
// Interleaved RoPE on a pre-split (hi, lo) buffer, in place.
// theta_j = 10000^(-j/1024) (denominator is the RoPE module's D_MODEL/2 = 1024
// regardless of input width). Pairs (2j, 2j+1). Reconstruct hi+lo, rotate,
// re-split (adds <= 2^-16 rel err).
// ---------------------------------------------------------------------------
template <int NC, int D2>
__global__ __launch_bounds__(256)
void rope_split_kernel(short* __restrict__ h, short* __restrict__ l) {
    const int idx = blockIdx.x * 256 + threadIdx.x;
    if (idx >= MROWS * D2) return;
    const int row = idx / D2;               // compile-time pow2 -> shift
    const int j   = idx - row * D2;
    const int pos = row & (SEQ - 1);
    const float theta = __expf(-(float)j * (9.210340371976184f / 1024.0f));
    float s, c;
    sincosf((float)pos * theta, &s, &c);
    const size_t base = (size_t)row * NC + 2 * j;
    short2 hh = *(short2*)&h[base];
    short2 ll = *(short2*)&l[base];
    const float e = bf2f(hh.x) + bf2f(ll.x);
    const float o = bf2f(hh.y) + bf2f(ll.y);
    const float re = e * c - o * s;
    const float ro = o * c + e * s;
    const short rh0 = f2bf_rn(re), rh1 = f2bf_rn(ro);
    *(short2*)&h[base] = make_short2(rh0, rh1);
    *(short2*)&l[base] = make_short2(f2bf_rn(re - bf2f(rh0)), f2bf_rn(ro - bf2f(rh1)));
}

// ---------------------------------------------------------------------------
// MFMA flash attention, bf16x3 split, fp32 softmax state.
// One block = (b, h, 64-row q-tile) covering BOTH nq query-heads (K/V staged
// once per k-tile). 4 waves x 16 q-rows; per-nq softmax state.
// ALL staging (Q, K, Vt) via global_load_lds width=16 with linear LDS dest +
// source-side chunk-XOR swizzle (rule #21, same algebra as mgemm). V arrives
// pre-transposed from the V GEMM as vt[KV_DIM][MROWS] hi/lo, so Vt rows are
// contiguous global memory — no gather.
// LDS (80 KB -> 2 blocks/CU): Q flat [64][128] hi/lo (nq bit rides above the
// 3 XOR bits), K hi/lo, Vt hi/lo, per-wave P (lgkmcnt(0) fence write->read).
// QK^T: A=Q-strip, B=K rows. Softmax in regs on C/D layout; row reduce =
// in-lane over 4 tiles + shfl_xor 1,2,4,8. PV: P round-trips per-wave LDS
// to reach A-frag layout; B=Vt rows.
// ---------------------------------------------------------------------------
__global__ __launch_bounds__(256)
void attn_mfma_kernel(const short* __restrict__ qh_g, const short* __restrict__ ql_g,
                      const short* __restrict__ kh_g, const short* __restrict__ kl_g,
                      const short* __restrict__ vth_g, const short* __restrict__ vtl_g,
                      short* __restrict__ aoh, short* __restrict__ aol) {
    __shared__ __align__(16) short Qh[64 * 128], Ql[64 * 128];
    __shared__ __align__(16) short Kh[64 * 64], Kl[64 * 64];
    __shared__ __align__(16) short Vth[64 * 64], Vtl[64 * 64];
    __shared__ __align__(16) short Ph[4][16 * 64], Pl[4][16 * 64];

    const int tid  = threadIdx.x;
    const int lane = tid & 63;
    const int wid  = tid >> 6;          // 0..3
    const int wq   = wid * 16;          // wave's q-row strip
    const int arow = lane & 15;
    const int kg   = lane >> 4;

    const int y  = blockIdx.y;          // 0..31
    const int b  = y >> 4;
    const int h  = y & 15;
    const int qrow0 = b * SEQ + blockIdx.x * 64;
    const int hcol0 = h * (N_QUERY * D_HEAD);   // head-pair base col in q/out
    const int kvcol = h * D_HEAD;               // base col in k / row in vt

    // ---- stage Q once: 64 rows x 128 cols (both nq) via global_load_lds.
    //      Row = 16 chunks; swizzle XORs only the low 3 chunk bits, so the
    //      nq bit (bit 3) is preserved.
#pragma unroll
    for (int i = 0; i < 4; ++i) {
        const int c    = i * 256 + tid;     // 0..1023
        const int r    = c >> 4;            // 0..63
        const int kc2  = c & 15;            // chunk-in-row 0..15
        const int kcs2 = kc2 ^ (r & 7);     // source-side swizzle (low 3 bits)
        const int db   = (i * 256 + (tid & 192)) * 8;   // wave-uniform dest
        const size_t src = (size_t)(qrow0 + r) * D_MODEL + hcol0 + kcs2 * 8;
        gload_lds16(&qh_g[src], &Qh[db]);
        gload_lds16(&ql_g[src], &Ql[db]);
    }

    f32x4 oacc[2][4];
    float mrow[2][4], lrow[2][4];
#pragma unroll
    for (int nq = 0; nq < 2; ++nq)
#pragma unroll
        for (int t = 0; t < 4; ++t) {
            oacc[nq][t] = (f32x4)0.f;
            mrow[nq][t] = -1e30f;
            lrow[nq][t] = 0.f;
        }
    const float scale = 0.125f;         // 1/sqrt(64)
    const size_t kvrow0 = (size_t)b * SEQ;

    for (int tt = 0; tt < SEQ / 64; ++tt) {
        __syncthreads();   // protect K/V LDS from previous iteration's readers
                           // (also drains the Q staging DMA on tt==0)
        // ---- stage K tile (64 kv-rows x 64 d) + Vt tile (64 d-rows x 64 kv)
        //      via global_load_lds, linear dest + source swizzle
#pragma unroll
        for (int i = 0; i < 2; ++i) {
            const int c   = i * 256 + tid;  // 0..511
            const int r   = c >> 3;         // K: kv-row / Vt: d-row
            const int kc  = c & 7;
            const int kcs = kc ^ (r & 7);
            const int db  = (i * 256 + (tid & 192)) * 8;
            const size_t sk = (kvrow0 + tt * 64 + r) * KV_DIM + kvcol + kcs * 8;
            const size_t sv = (size_t)(kvcol + r) * MROWS + kvrow0 + tt * 64 + kcs * 8;
            gload_lds16(&kh_g[sk],  &Kh[db]);
            gload_lds16(&kl_g[sk],  &Kl[db]);
            gload_lds16(&vth_g[sv], &Vth[db]);
            gload_lds16(&vtl_g[sv], &Vtl[db]);
        }
        __syncthreads();   // drains vmcnt(0) -> LDS-DMA complete

        // ---- both nq heads share the staged K/V
#pragma unroll
        for (int nq = 0; nq < 2; ++nq) {
            // ---- S = Q K^T (strip 16 q-rows x 64 kv), bf16x3
            f32x4 sacc[4];
#pragma unroll
            for (int t = 0; t < 4; ++t) sacc[t] = (f32x4)0.f;
#pragma unroll
            for (int kk = 0; kk < 2; ++kk) {
                const int kcb = kk * 4 + kg;
                const int rq  = wq + arow;
                const int ia  = rq * 128 + nq * 64 + ((kcb ^ (rq & 7)) << 3);
                const short8x qh = *(const short8x*)&Qh[ia];
                const short8x ql = *(const short8x*)&Ql[ia];
#pragma unroll
                for (int t = 0; t < 4; ++t) {
                    const int rk = t * 16 + arow;
                    const int ib = rk * 64 + ((kcb ^ (rk & 7)) << 3);
                    const short8x kh = *(const short8x*)&Kh[ib];
                    const short8x kl = *(const short8x*)&Kl[ib];
                    sacc[t] = __builtin_amdgcn_mfma_f32_16x16x32_bf16(qh, kl, sacc[t], 0, 0, 0);
                    sacc[t] = __builtin_amdgcn_mfma_f32_16x16x32_bf16(ql, kh, sacc[t], 0, 0, 0);
                    sacc[t] = __builtin_amdgcn_mfma_f32_16x16x32_bf16(qh, kh, sacc[t], 0, 0, 0);
                }
            }

            // ---- online softmax on C/D layout (lane: 4 q-rows x 4 kv-tiles)
            float pv[4][4];             // pv[t][jj] = P values
#pragma unroll
            for (int jj = 0; jj < 4; ++jj) {
                float mx = sacc[0][jj] * scale;
#pragma unroll
                for (int t = 1; t < 4; ++t) mx = fmaxf(mx, sacc[t][jj] * scale);
                mx = fmaxf(mx, __shfl_xor(mx, 1));
                mx = fmaxf(mx, __shfl_xor(mx, 2));
                mx = fmaxf(mx, __shfl_xor(mx, 4));
                mx = fmaxf(mx, __shfl_xor(mx, 8));
                const float mnew  = fmaxf(mrow[nq][jj], mx);
                const float alpha = __expf(mrow[nq][jj] - mnew);
                float ls = 0.f;
#pragma unroll
                for (int t = 0; t < 4; ++t) {
                    float p = __expf(sacc[t][jj] * scale - mnew);
                    pv[t][jj] = p;
                    ls += p;
                }
                ls += __shfl_xor(ls, 1);
                ls += __shfl_xor(ls, 2);
                ls += __shfl_xor(ls, 4);
                ls += __shfl_xor(ls, 8);
                lrow[nq][jj] = lrow[nq][jj] * alpha + ls;
                mrow[nq][jj] = mnew;
#pragma unroll
                for (int t = 0; t < 4; ++t) oacc[nq][t][jj] *= alpha;
            }

            // ---- P -> per-wave LDS (bf16 hi/lo), C/D layout -> A-frag layout
#pragma unroll
            for (int t = 0; t < 4; ++t)
#pragma unroll
                for (int jj = 0; jj < 4; ++jj) {
                    const int qq  = (lane >> 4) * 4 + jj;        // 0..15
                    const int kv  = t * 16 + (lane & 15);        // 0..63
                    const int idx = qq * 64 + (((kv >> 3) ^ (qq & 7)) << 3) + (kv & 7);
                    const short hb = f2bf_rn(pv[t][jj]);
                    Ph[wid][idx] = hb;
                    Pl[wid][idx] = f2bf_rn(pv[t][jj] - bf2f(hb));
                }
            asm volatile("s_waitcnt lgkmcnt(0)" ::: "memory");

            // ---- O += P V  (A = P from per-wave LDS, B = Vt rows), bf16x3
#pragma unroll
            for (int kk = 0; kk < 2; ++kk) {
                const int kcb = kk * 4 + kg;
                const int ip  = arow * 64 + ((kcb ^ (arow & 7)) << 3);
                const short8x ph = *(const short8x*)&Ph[wid][ip];
                const short8x pl = *(const short8x*)&Pl[wid][ip];
#pragma unroll
                for (int t = 0; t < 4; ++t) {
                    const int rv = t * 16 + arow;
                    const int iv = rv * 64 + ((kcb ^ (rv & 7)) << 3);
                    const short8x vh = *(const short8x*)&Vth[iv];
                    const short8x vl = *(const short8x*)&Vtl[iv];
                    oacc[nq][t] = __builtin_amdgcn_mfma_f32_16x16x32_bf16(ph, vl, oacc[nq][t], 0, 0, 0);
                    oacc[nq][t] = __builtin_amdgcn_mfma_f32_16x16x32_bf16(pl, vh, oacc[nq][t], 0, 0, 0);
                    oacc[nq][t] = __builtin_amdgcn_mfma_f32_16x16x32_bf16(ph, vh, oacc[nq][t], 0, 0, 0);
                }
            }
        }
    }

    // ---- epilogue: divide by l, store split (C/D mapping as mgemm)
#pragma unroll
    for (int nq = 0; nq < 2; ++nq)
#pragma unroll
        for (int jj = 0; jj < 4; ++jj) {
            const float inv = 1.f / lrow[nq][jj];
            const int row = qrow0 + wq + (lane >> 4) * 4 + jj;
#pragma unroll
            for (int t = 0; t < 4; ++t) {
                const size_t off = (size_t)row * D_MODEL + hcol0 + nq * D_HEAD
                                 + t * 16 + (lane & 15);
                const float val = oacc[nq][t][jj] * inv;
                const short hb = f2bf_rn(val);
                aoh[off] = hb;
                aol[off] = f2bf_rn(val - bf2f(hb));
            }
        }
}

// ---------------------------------------------------------------------------
extern "C" void kernel_launch(void* const* d_in, const int* in_sizes, int n_in,
                              void* d_out, int out_size, void* d_ws, size_t ws_size,
                              hipStream_t stream) {
    const float* x  = (const float*)d_in[0];
    const float* Wq = (const float*)d_in[1];
    const float* Wk = (const float*)d_in[2];
    const float* Wv = (const float*)d_in[3];
    const float* Wo = (const float*)d_in[4];
    float* out = (float*)d_out;

    // workspace layout (MiB offsets), total 144 MiB.
    // aoh/aol reuse the xh/xl region: x is dead after the QKV GEMMs, and
    // attention (the writer) is stream-ordered after them.
    // Weight buffers hold the TRANSPOSED split ([N][K]).
    // vh/vl hold V TRANSPOSED as vt[KV_DIM][MROWS] (written by the V GEMM).
    const size_t MiB = (size_t)1 << 20;
    char* ws = (char*)d_ws;
    short* qh  = (short*)(ws + 0   * MiB);
    short* ql  = (short*)(ws + 16  * MiB);
    short* kh  = (short*)(ws + 32  * MiB);
    short* kl  = (short*)(ws + 40  * MiB);
    short* vth = (short*)(ws + 48  * MiB);
    short* vtl = (short*)(ws + 56  * MiB);
    short* xh  = (short*)(ws + 64  * MiB);
    short* xl  = (short*)(ws + 80  * MiB);
    short* aoh = (short*)(ws + 64  * MiB);   // reuse xh
    short* aol = (short*)(ws + 80  * MiB);   // reuse xl
    short* Wqh = (short*)(ws + 96  * MiB);
    short* Wql = (short*)(ws + 104 * MiB);
    short* Wkh = (short*)(ws + 112 * MiB);
    short* Wkl = (short*)(ws + 116 * MiB);
    short* Wvh = (short*)(ws + 120 * MiB);
    short* Wvl = (short*)(ws + 124 * MiB);
    short* Woh = (short*)(ws + 128 * MiB);
    short* Wol = (short*)(ws + 136 * MiB);

    // ---- split x (row-major) + split-transpose all weights (one-shot)
    split_kernel<<<(MROWS * D_MODEL) / 1024, 256, 0, stream>>>(x, xh, xl, MROWS * D_MODEL);
    split_tr_kernel<<<dim3(D_MODEL / 32, D_MODEL / 32), 256, 0, stream>>>(Wq, Wqh, Wql, D_MODEL, D_MODEL);
    split_tr_kernel<<<dim3(KV_DIM  / 32, D_MODEL / 32), 256, 0, stream>>>(Wk, Wkh, Wkl, D_MODEL, KV_DIM);
    split_tr_kernel<<<dim3(KV_DIM  / 32, D_MODEL / 32), 256, 0, stream>>>(Wv, Wvh, Wvl, D_MODEL, KV_DIM);
    split_tr_kernel<<<dim3(D_MODEL / 32, D_MODEL / 32), 256, 0, stream>>>(Wo, Woh, Wol, D_MODEL, D_MODEL);

    // ---- QKV projections (bf16x3 MFMA, B^T inputs)
    mgemm_bf_kernel<1><<<dim3(D_MODEL / 128, MROWS / 128), 256, 0, stream>>>(
        xh, xl, Wqh, Wql, nullptr, qh, ql, MROWS, D_MODEL, D_MODEL);
    mgemm_bf_kernel<1><<<dim3(KV_DIM / 128, MROWS / 128), 256, 0, stream>>>(
        xh, xl, Wkh, Wkl, nullptr, kh, kl, MROWS, KV_DIM, D_MODEL);
    mgemm_bf_kernel<2><<<dim3(KV_DIM / 128, MROWS / 128), 256, 0, stream>>>(
        xh, xl, Wvh, Wvl, nullptr, vth, vtl, MROWS, KV_DIM, D_MODEL);

    // ---- RoPE in place on split buffers
    rope_split_kernel<D_MODEL, 1024><<<(MROWS * 1024) / 256, 256, 0, stream>>>(qh, ql);
    rope_split_kernel<KV_DIM,   512><<<(MROWS * 512)  / 256, 256, 0, stream>>>(kh, kl);

    // ---- attention: grid (q-tiles, b*h), both nq per block, MFMA flash
    attn_mfma_kernel<<<dim3(SEQ / 64, BATCH * N_HEAD), 256, 0, stream>>>(
        qh, ql, kh, kl, vth, vtl, aoh, aol);

    // ---- output projection (bf16x3 MFMA, B^T input, fp32 output)
    mgemm_bf_kernel<0><<<dim3(D_MODEL / 128, MROWS / 128), 256, 0, stream>>>(
        aoh, aol, Woh, Wol, out, nullptr, nullptr, MROWS, D_MODEL, D_MODEL);
}

// Round 9
// 793.676 us; speedup vs baseline: 1.0407x; 1.0407x over previous
//
#include <hip/hip_runtime.h>
#include <hip/hip_bf16.h>
#include <math.h>

#define D_MODEL 2048
#define KV_DIM  1024
#define N_HEAD  16
#define N_QUERY 2
#define D_HEAD  64
#define BATCH   2
#define SEQ     2048
#define MROWS   (BATCH * SEQ)   // 4096 flattened (b, s) rows

typedef __attribute__((ext_vector_type(8))) short short8x;   // 8 bf16 = 4 VGPR
typedef __attribute__((ext_vector_type(4))) float f32x4;

// self-contained bf16 round-to-nearest-even (no header-API dependency)
__device__ __forceinline__ short f2bf_rn(float f) {
    unsigned u = __float_as_uint(f);
    unsigned r = (u + 0x7fffu + ((u >> 16) & 1u)) >> 16;
    return (short)r;
}
__device__ __forceinline__ float bf2f(short s) {
    return __uint_as_float(((unsigned)(unsigned short)s) << 16);
}

// async global->LDS, 16 B per lane. LDS dest is wave-uniform base + lane*16
// (m104/m108), so pass a wave-uniform LDS pointer; global src is per-lane.
__device__ __forceinline__ void gload_lds16(const short* g, short* l) {
    __builtin_amdgcn_global_load_lds(
        (const __attribute__((address_space(1))) void*)g,
        (__attribute__((address_space(3))) void*)l,
        16, 0, 0);
}

// ---------------------------------------------------------------------------
// fp32 -> (hi, lo) bf16 split, elementwise. n must be a multiple of 4.
// ---------------------------------------------------------------------------
__global__ __launch_bounds__(256)
void split_kernel(const float* __restrict__ in, short* __restrict__ h,
                  short* __restrict__ l, int n) {
    const int i = (blockIdx.x * 256 + threadIdx.x) * 4;
    if (i >= n) return;
    float4 v = *(const float4*)&in[i];
    short4 hv, lv;
    hv.x = f2bf_rn(v.x); lv.x = f2bf_rn(v.x - bf2f(hv.x));
    hv.y = f2bf_rn(v.y); lv.y = f2bf_rn(v.y - bf2f(hv.y));
    hv.z = f2bf_rn(v.z); lv.z = f2bf_rn(v.z - bf2f(hv.z));
    hv.w = f2bf_rn(v.w); lv.w = f2bf_rn(v.w - bf2f(hv.w));
    *(short4*)&h[i] = hv;
    *(short4*)&l[i] = lv;
}

// ---------------------------------------------------------------------------
// transpose + split: in fp32 [K][N] -> h/l bf16 [N][K]. 32x32 LDS tile
// (33-padded), coalesced on read (N-fast) and write (K-fast).
// ---------------------------------------------------------------------------
__global__ __launch_bounds__(256)
void split_tr_kernel(const float* __restrict__ in, short* __restrict__ h,
                     short* __restrict__ l, int K, int N) {
    __shared__ float t[32][33];
    const int k0 = blockIdx.y * 32;
    const int n0 = blockIdx.x * 32;
    const int c  = threadIdx.x & 31;
    const int r0 = threadIdx.x >> 5;    // 0..7
#pragma unroll
    for (int i = 0; i < 4; ++i) {
        const int r = r0 + i * 8;
        t[r][c] = in[(size_t)(k0 + r) * N + n0 + c];
    }
    __syncthreads();
#pragma unroll
    for (int i = 0; i < 4; ++i) {
        const int r = r0 + i * 8;           // output n-offset
        const float f = t[c][r];            // = in[k0+c][n0+r]
        const short hb = f2bf_rn(f);
        const size_t off = (size_t)(n0 + r) * K + k0 + c;
        h[off] = hb;
        l[off] = f2bf_rn(f - bf2f(hb));
    }
}

// ---------------------------------------------------------------------------
// bf16x3-split MFMA GEMM on pre-split inputs: C = A @ B, ~5e-5 rel err.
// A as (Ah,Al) [M][K] bf16, B pre-TRANSPOSED as (Bth,Btl) [N][K] bf16.
// 128x128 tile, BK=64, 256 thr (4 waves, 2x2 of 64x64), mfma_f32_16x16x32_bf16.
// Staging uses global_load_lds width=16: LDS dest is LINEAR (chunk c at byte
// c*16); the chunk-XOR swizzle is applied to the GLOBAL source address
// (both-sides-or-neither, guide rule #21). Position (r,v) holds global chunk
// (r, v^(r&7)), so the fragment read at (r, u^(r&7)) retrieves logical chunk
// (r,u), and the hot LDS reads stay bank-conflict-free.
// MODE: 0 = fp32 C; 1 = split (Ch,Cl) [M][N]; 2 = split TRANSPOSED [N][M]
// (for V: attention consumes Vt[d][s] rows directly).
// ---------------------------------------------------------------------------
template <int MODE>
__global__ __launch_bounds__(256)
void mgemm_bf_kernel(const short* __restrict__ Ah_g, const short* __restrict__ Al_g,
                     const short* __restrict__ Bth_g, const short* __restrict__ Btl_g,
                     float* __restrict__ C, short* __restrict__ Ch, short* __restrict__ Cl,
                     int M, int N, int K) {
    __shared__ __align__(16) short Ah[128 * 64];
    __shared__ __align__(16) short Al[128 * 64];
    __shared__ __align__(16) short Bh[128 * 64];
    __shared__ __align__(16) short Bl[128 * 64];

    const int tid  = threadIdx.x;
    const int lane = tid & 63;
    const int wid  = tid >> 6;
    const int wm   = (wid >> 1) * 64;   // wave row offset in tile
    const int wn   = (wid & 1) * 64;    // wave col offset in tile
    const int row0 = blockIdx.y * 128;
    const int col0 = blockIdx.x * 128;
    const int arow = lane & 15;
    const int kg   = lane >> 4;         // 0..3 -> k-chunk within MFMA step

    f32x4 acc[4][4];
#pragma unroll
    for (int m = 0; m < 4; ++m)
#pragma unroll
        for (int n = 0; n < 4; ++n) acc[m][n] = (f32x4)0.f;

    for (int kt = 0; kt < K; kt += 64) {
        // ---- stage A + Bt via global_load_lds: linear LDS dest, pre-swizzled
        //      global source (kcs = kc ^ (r&7) permutes 16B sub-chunks within
        //      the same 128B row segment -> coalescing preserved)
#pragma unroll
        for (int i = 0; i < 4; ++i) {
            const int c   = i * 256 + tid;      // 0..1023 chunk id
            const int r   = c >> 3;             // 0..127
            const int kc  = c & 7;              // 8-elem chunk 0..7
            const int kcs = kc ^ (r & 7);       // source-side swizzle
            const int db  = (i * 256 + (tid & 192)) * 8;  // wave-uniform dest (shorts)
            const size_t sa = (size_t)(row0 + r) * K + kt + kcs * 8;
            const size_t sb = (size_t)(col0 + r) * K + kt + kcs * 8;
            gload_lds16(&Ah_g[sa],  &Ah[db]);
            gload_lds16(&Al_g[sa],  &Al[db]);
            gload_lds16(&Bth_g[sb], &Bh[db]);
            gload_lds16(&Btl_g[sb], &Bl[db]);
        }
        __syncthreads();   // drains vmcnt(0) -> LDS-DMA complete

        // ---- 2 MFMA K-steps of 32; 3 MFMAs per (m,n) for the bf16x3 split
#pragma unroll
        for (int kk = 0; kk < 2; ++kk) {
            const int kcb = kk * 4 + kg;
            short8x ah[4], al[4];
#pragma unroll
            for (int m = 0; m < 4; ++m) {
                const int r   = wm + m * 16 + arow;
                const int idx = r * 64 + ((kcb ^ (r & 7)) << 3);
                ah[m] = *(const short8x*)&Ah[idx];
                al[m] = *(const short8x*)&Al[idx];
            }
#pragma unroll
            for (int n = 0; n < 4; ++n) {
                const int rb   = wn + n * 16 + arow;
                const int idxb = rb * 64 + ((kcb ^ (rb & 7)) << 3);
                short8x bh = *(const short8x*)&Bh[idxb];
                short8x bl = *(const short8x*)&Bl[idxb];
#pragma unroll
                for (int m = 0; m < 4; ++m) {
                    acc[m][n] = __builtin_amdgcn_mfma_f32_16x16x32_bf16(ah[m], bl, acc[m][n], 0, 0, 0);
                    acc[m][n] = __builtin_amdgcn_mfma_f32_16x16x32_bf16(al[m], bh, acc[m][n], 0, 0, 0);
                    acc[m][n] = __builtin_amdgcn_mfma_f32_16x16x32_bf16(ah[m], bh, acc[m][n], 0, 0, 0);
                }
            }
        }
        __syncthreads();
    }

    // ---- epilogue: C/D mapping col=lane&15, row=(lane>>4)*4+j [m89 verified]
#pragma unroll
    for (int m = 0; m < 4; ++m)
#pragma unroll
        for (int n = 0; n < 4; ++n) {
            const int row = row0 + wm + m * 16 + (lane >> 4) * 4;
            const int col = col0 + wn + n * 16 + (lane & 15);
            if (MODE == 2) {
                // transposed split store: Ct[col][row], 4 j-values contiguous
                const float v0 = acc[m][n][0], v1 = acc[m][n][1];
                const float v2 = acc[m][n][2], v3 = acc[m][n][3];
                const short h0 = f2bf_rn(v0), h1 = f2bf_rn(v1);
                const short h2 = f2bf_rn(v2), h3 = f2bf_rn(v3);
                const size_t off = (size_t)col * M + row;
                *(short4*)&Ch[off] = make_short4(h0, h1, h2, h3);
                *(short4*)&Cl[off] = make_short4(
                    f2bf_rn(v0 - bf2f(h0)), f2bf_rn(v1 - bf2f(h1)),
                    f2bf_rn(v2 - bf2f(h2)), f2bf_rn(v3 - bf2f(h3)));
            } else {
#pragma unroll
                for (int j = 0; j < 4; ++j) {
                    const size_t off = (size_t)(row + j) * N + col;
                    if (MODE == 1) {
                        const float val = acc[m][n][j];
                        const short hb = f2bf_rn(val);
                        Ch[off] = hb;
                        Cl[off] = f2bf_rn(val - bf2f(hb));
                    } else {
                        C[off] = acc[m][n][j];
                    }
                }
            }
        }
}

// ---------------------------------------------------------------------------
// Interleaved RoPE on a pre-split (hi, lo) buffer, in place.
// theta_j = 10000^(-j/1024) (denominator is the RoPE module's D_MODEL/2 = 1024
// regardless of input width). Pairs (2j, 2j+1). Reconstruct hi+lo, rotate,
// re-split (adds <= 2^-16 rel err).
// ---------------------------------------------------------------------------
template <int NC, int D2>
__global__ __launch_bounds__(256)
void rope_split_kernel(short* __restrict__ h, short* __restrict__ l) {
    const int idx = blockIdx.x * 256 + threadIdx.x;
    if (idx >= MROWS * D2) return;
    const int row = idx / D2;               // compile-time pow2 -> shift
    const int j   = idx - row * D2;
    const int pos = row & (SEQ - 1);
    const float theta = __expf(-(float)j * (9.210340371976184f / 1024.0f));
    float s, c;
    sincosf((float)pos * theta, &s, &c);
    const size_t base = (size_t)row * NC + 2 * j;
    short2 hh = *(short2*)&h[base];
    short2 ll = *(short2*)&l[base];
    const float e = bf2f(hh.x) + bf2f(ll.x);
    const float o = bf2f(hh.y) + bf2f(ll.y);
    const float re = e * c - o * s;
    const float ro = o * c + e * s;
    const short rh0 = f2bf_rn(re), rh1 = f2bf_rn(ro);
    *(short2*)&h[base] = make_short2(rh0, rh1);
    *(short2*)&l[base] = make_short2(f2bf_rn(re - bf2f(rh0)), f2bf_rn(ro - bf2f(rh1)));
}

// ---------------------------------------------------------------------------
// MFMA flash attention, bf16x3 split, fp32 softmax state.
// OCCUPANCY RESTRUCTURE (r8: Occupancy 21%, MfmaUtil 23%, HBM 6% -> latency
// bound at 80 KB LDS = 2 blk/CU x 4 waves = 8 waves/CU):
//   * 512 threads = 8 waves = 4 q-strips x 2 nq; each wave owns ONE nq
//     (no serial nq loop).
//   * Q lives in REGISTERS (each lane holds exactly its A-fragments:
//     2 kk x short8x hi/lo = 16 VGPR, loaded once from global) -> Q LDS and
//     its staging eliminated.
//   * LDS 64 KB (K 16 + Vt 16 + per-wave P 32) -> 2 blk/CU x 8 waves =
//     16 waves/CU (50% cap, was 25%).
// K/Vt staged via global_load_lds width=16, linear dest + source-side
// chunk-XOR swizzle (rule #21). V arrives pre-transposed as vt[KV_DIM][MROWS].
// QK^T: A=Q-regs, B=K rows. Softmax in regs on C/D layout; row reduce =
// in-lane over 4 tiles + shfl_xor 1,2,4,8. PV: P round-trips per-wave LDS
// (lgkmcnt(0) fence) to reach A-frag layout; B=Vt rows.
// ---------------------------------------------------------------------------
__global__ __launch_bounds__(512, 4)
void attn_mfma_kernel(const short* __restrict__ qh_g, const short* __restrict__ ql_g,
                      const short* __restrict__ kh_g, const short* __restrict__ kl_g,
                      const short* __restrict__ vth_g, const short* __restrict__ vtl_g,
                      short* __restrict__ aoh, short* __restrict__ aol) {
    __shared__ __align__(16) short Kh[64 * 64], Kl[64 * 64];
    __shared__ __align__(16) short Vth[64 * 64], Vtl[64 * 64];
    __shared__ __align__(16) short Ph[8][16 * 64], Pl[8][16 * 64];

    const int tid  = threadIdx.x;
    const int lane = tid & 63;
    const int wid  = tid >> 6;          // 0..7
    const int strip = wid >> 1;         // 0..3 -> q-row strip
    const int nq    = wid & 1;          // query head within GQA pair
    const int wq   = strip * 16;
    const int arow = lane & 15;
    const int kg   = lane >> 4;

    const int y  = blockIdx.y;          // 0..31
    const int b  = y >> 4;
    const int h  = y & 15;
    const int qrow0 = b * SEQ + blockIdx.x * 64;
    const int hcol0 = h * (N_QUERY * D_HEAD);   // head-pair base col in q/out
    const int kvcol = h * D_HEAD;               // base col in k / row in vt

    // ---- Q fragments directly to registers (A-frag: row=arow, k=kcb*8..+7)
    short8x qhr[2], qlr[2];
    {
        const size_t qbase = (size_t)(qrow0 + wq + arow) * D_MODEL + hcol0 + nq * D_HEAD;
#pragma unroll
        for (int kk = 0; kk < 2; ++kk) {
            const int kcb = kk * 4 + kg;
            qhr[kk] = *(const short8x*)&qh_g[qbase + kcb * 8];
            qlr[kk] = *(const short8x*)&ql_g[qbase + kcb * 8];
        }
    }

    f32x4 oacc[4];
    float mrow[4], lrow[4];
#pragma unroll
    for (int t = 0; t < 4; ++t) {
        oacc[t] = (f32x4)0.f;
        mrow[t] = -1e30f;
        lrow[t] = 0.f;
    }
    const float scale = 0.125f;         // 1/sqrt(64)
    const size_t kvrow0 = (size_t)b * SEQ;

    for (int tt = 0; tt < SEQ / 64; ++tt) {
        __syncthreads();   // protect K/V LDS from previous iteration's readers
        // ---- stage K tile (64 kv-rows x 64 d) + Vt tile (64 d-rows x 64 kv)
        //      via global_load_lds: 512 chunks, one per thread per array
        {
            const int r   = tid >> 3;       // 0..63
            const int kc  = tid & 7;
            const int kcs = kc ^ (r & 7);   // source-side swizzle
            const int db  = (tid & 448) * 8;   // wave-uniform dest (shorts)
            const size_t sk = (kvrow0 + tt * 64 + r) * KV_DIM + kvcol + kcs * 8;
            const size_t sv = (size_t)(kvcol + r) * MROWS + kvrow0 + tt * 64 + kcs * 8;
            gload_lds16(&kh_g[sk],  &Kh[db]);
            gload_lds16(&kl_g[sk],  &Kl[db]);
            gload_lds16(&vth_g[sv], &Vth[db]);
            gload_lds16(&vtl_g[sv], &Vtl[db]);
        }
        __syncthreads();   // drains vmcnt(0) -> LDS-DMA complete

        // ---- S = Q K^T (strip 16 q-rows x 64 kv), bf16x3, Q from regs
        f32x4 sacc[4];
#pragma unroll
        for (int t = 0; t < 4; ++t) sacc[t] = (f32x4)0.f;
#pragma unroll
        for (int kk = 0; kk < 2; ++kk) {
            const int kcb = kk * 4 + kg;
            const short8x qh = qhr[kk];
            const short8x ql = qlr[kk];
#pragma unroll
            for (int t = 0; t < 4; ++t) {
                const int rk = t * 16 + arow;
                const int ib = rk * 64 + ((kcb ^ (rk & 7)) << 3);
                const short8x kh = *(const short8x*)&Kh[ib];
                const short8x kl = *(const short8x*)&Kl[ib];
                sacc[t] = __builtin_amdgcn_mfma_f32_16x16x32_bf16(qh, kl, sacc[t], 0, 0, 0);
                sacc[t] = __builtin_amdgcn_mfma_f32_16x16x32_bf16(ql, kh, sacc[t], 0, 0, 0);
                sacc[t] = __builtin_amdgcn_mfma_f32_16x16x32_bf16(qh, kh, sacc[t], 0, 0, 0);
            }
        }

        // ---- online softmax on C/D layout (lane: 4 q-rows x 4 kv-tiles)
        float pv[4][4];             // pv[t][jj] = P values
#pragma unroll
        for (int jj = 0; jj < 4; ++jj) {
            float mx = sacc[0][jj] * scale;
#pragma unroll
            for (int t = 1; t < 4; ++t) mx = fmaxf(mx, sacc[t][jj] * scale);
            mx = fmaxf(mx, __shfl_xor(mx, 1));
            mx = fmaxf(mx, __shfl_xor(mx, 2));
            mx = fmaxf(mx, __shfl_xor(mx, 4));
            mx = fmaxf(mx, __shfl_xor(mx, 8));
            const float mnew  = fmaxf(mrow[jj], mx);
            const float alpha = __expf(mrow[jj] - mnew);
            float ls = 0.f;
#pragma unroll
            for (int t = 0; t < 4; ++t) {
                float p = __expf(sacc[t][jj] * scale - mnew);
                pv[t][jj] = p;
                ls += p;
            }
            ls += __shfl_xor(ls, 1);
            ls += __shfl_xor(ls, 2);
            ls += __shfl_xor(ls, 4);
            ls += __shfl_xor(ls, 8);
            lrow[jj] = lrow[jj] * alpha + ls;
            mrow[jj] = mnew;
#pragma unroll
            for (int t = 0; t < 4; ++t) oacc[t][jj] *= alpha;
        }

        // ---- P -> per-wave LDS (bf16 hi/lo), C/D layout -> A-frag layout
#pragma unroll
        for (int t = 0; t < 4; ++t)
#pragma unroll
            for (int jj = 0; jj < 4; ++jj) {
                const int qq  = (lane >> 4) * 4 + jj;        // 0..15
                const int kv  = t * 16 + (lane & 15);        // 0..63
                const int idx = qq * 64 + (((kv >> 3) ^ (qq & 7)) << 3) + (kv & 7);
                const short hb = f2bf_rn(pv[t][jj]);
                Ph[wid][idx] = hb;
                Pl[wid][idx] = f2bf_rn(pv[t][jj] - bf2f(hb));
            }
        asm volatile("s_waitcnt lgkmcnt(0)" ::: "memory");

        // ---- O += P V  (A = P from per-wave LDS, B = Vt rows), bf16x3
#pragma unroll
        for (int kk = 0; kk < 2; ++kk) {
            const int kcb = kk * 4 + kg;
            const int ip  = arow * 64 + ((kcb ^ (arow & 7)) << 3);
            const short8x ph = *(const short8x*)&Ph[wid][ip];
            const short8x pl = *(const short8x*)&Pl[wid][ip];
#pragma unroll
            for (int t = 0; t < 4; ++t) {
                const int rv = t * 16 + arow;
                const int iv = rv * 64 + ((kcb ^ (rv & 7)) << 3);
                const short8x vh = *(const short8x*)&Vth[iv];
                const short8x vl = *(const short8x*)&Vtl[iv];
                oacc[t] = __builtin_amdgcn_mfma_f32_16x16x32_bf16(ph, vl, oacc[t], 0, 0, 0);
                oacc[t] = __builtin_amdgcn_mfma_f32_16x16x32_bf16(pl, vh, oacc[t], 0, 0, 0);
                oacc[t] = __builtin_amdgcn_mfma_f32_16x16x32_bf16(ph, vh, oacc[t], 0, 0, 0);
            }
        }
    }

    // ---- epilogue: divide by l, store split (C/D mapping as mgemm)
#pragma unroll
    for (int jj = 0; jj < 4; ++jj) {
        const float inv = 1.f / lrow[jj];
        const int row = qrow0 + wq + (lane >> 4) * 4 + jj;
#pragma unroll
        for (int t = 0; t < 4; ++t) {
            const size_t off = (size_t)row * D_MODEL + hcol0 + nq * D_HEAD
                             + t * 16 + (lane & 15);
            const float val = oacc[t][jj] * inv;
            const short hb = f2bf_rn(val);
            aoh[off] = hb;
            aol[off] = f2bf_rn(val - bf2f(hb));
        }
    }
}

// ---------------------------------------------------------------------------
extern "C" void kernel_launch(void* const* d_in, const int* in_sizes, int n_in,
                              void* d_out, int out_size, void* d_ws, size_t ws_size,
                              hipStream_t stream) {
    const float* x  = (const float*)d_in[0];
    const float* Wq = (const float*)d_in[1];
    const float* Wk = (const float*)d_in[2];
    const float* Wv = (const float*)d_in[3];
    const float* Wo = (const float*)d_in[4];
    float* out = (float*)d_out;

    // workspace layout (MiB offsets), total 144 MiB.
    // aoh/aol reuse the xh/xl region: x is dead after the QKV GEMMs, and
    // attention (the writer) is stream-ordered after them.
    // Weight buffers hold the TRANSPOSED split ([N][K]).
    // vth/vtl hold V TRANSPOSED as vt[KV_DIM][MROWS] (written by the V GEMM).
    const size_t MiB = (size_t)1 << 20;
    char* ws = (char*)d_ws;
    short* qh  = (short*)(ws + 0   * MiB);
    short* ql  = (short*)(ws + 16  * MiB);
    short* kh  = (short*)(ws + 32  * MiB);
    short* kl  = (short*)(ws + 40  * MiB);
    short* vth = (short*)(ws + 48  * MiB);
    short* vtl = (short*)(ws + 56  * MiB);
    short* xh  = (short*)(ws + 64  * MiB);
    short* xl  = (short*)(ws + 80  * MiB);
    short* aoh = (short*)(ws + 64  * MiB);   // reuse xh
    short* aol = (short*)(ws + 80  * MiB);   // reuse xl
    short* Wqh = (short*)(ws + 96  * MiB);
    short* Wql = (short*)(ws + 104 * MiB);
    short* Wkh = (short*)(ws + 112 * MiB);
    short* Wkl = (short*)(ws + 116 * MiB);
    short* Wvh = (short*)(ws + 120 * MiB);
    short* Wvl = (short*)(ws + 124 * MiB);
    short* Woh = (short*)(ws + 128 * MiB);
    short* Wol = (short*)(ws + 136 * MiB);

    // ---- split x (row-major) + split-transpose all weights (one-shot)
    split_kernel<<<(MROWS * D_MODEL) / 1024, 256, 0, stream>>>(x, xh, xl, MROWS * D_MODEL);
    split_tr_kernel<<<dim3(D_MODEL / 32, D_MODEL / 32), 256, 0, stream>>>(Wq, Wqh, Wql, D_MODEL, D_MODEL);
    split_tr_kernel<<<dim3(KV_DIM  / 32, D_MODEL / 32), 256, 0, stream>>>(Wk, Wkh, Wkl, D_MODEL, KV_DIM);
    split_tr_kernel<<<dim3(KV_DIM  / 32, D_MODEL / 32), 256, 0, stream>>>(Wv, Wvh, Wvl, D_MODEL, KV_DIM);
    split_tr_kernel<<<dim3(D_MODEL / 32, D_MODEL / 32), 256, 0, stream>>>(Wo, Woh, Wol, D_MODEL, D_MODEL);

    // ---- QKV projections (bf16x3 MFMA, B^T inputs)
    mgemm_bf_kernel<1><<<dim3(D_MODEL / 128, MROWS / 128), 256, 0, stream>>>(
        xh, xl, Wqh, Wql, nullptr, qh, ql, MROWS, D_MODEL, D_MODEL);
    mgemm_bf_kernel<1><<<dim3(KV_DIM / 128, MROWS / 128), 256, 0, stream>>>(
        xh, xl, Wkh, Wkl, nullptr, kh, kl, MROWS, KV_DIM, D_MODEL);
    mgemm_bf_kernel<2><<<dim3(KV_DIM / 128, MROWS / 128), 256, 0, stream>>>(
        xh, xl, Wvh, Wvl, nullptr, vth, vtl, MROWS, KV_DIM, D_MODEL);

    // ---- RoPE in place on split buffers
    rope_split_kernel<D_MODEL, 1024><<<(MROWS * 1024) / 256, 256, 0, stream>>>(qh, ql);
    rope_split_kernel<KV_DIM,   512><<<(MROWS * 512)  / 256, 256, 0, stream>>>(kh, kl);

    // ---- attention: grid (q-tiles, b*h), 512 thr = 4 strips x 2 nq
    attn_mfma_kernel<<<dim3(SEQ / 64, BATCH * N_HEAD), 512, 0, stream>>>(
        qh, ql, kh, kl, vth, vtl, aoh, aol);

    // ---- output projection (bf16x3 MFMA, B^T input, fp32 output)
    mgemm_bf_kernel<0><<<dim3(D_MODEL / 128, MROWS / 128), 256, 0, stream>>>(
        aoh, aol, Woh, Wol, out, nullptr, nullptr, MROWS, D_MODEL, D_MODEL);
}